// Round 1
// baseline (172.373 us; speedup 1.0000x reference)
//
#include <hip/hip_runtime.h>

// PFNN: 4 branches of 3->32->32->32->1 tanh MLP, N=1M points, fp32 in/out.
// Round 8: layer-0 moved onto the MFMA pipe. Counters show VALU-issue bound
// (VALUBusy ~91%, MfmaUtil 6.3%); L0's 384 v_fma + ~128 VMEM weight loads +
// loop glue per wave were the largest removable VALU bucket after tanh.
//   - L0 as 16x16x32 MFMA with hi/lo f16 split of x (k-slots per quad:
//     [xh0,xh1,xh2,xl0,xl1,xl2,0,0]; B rows quad0=Wh(x2), quad1=Wl) ->
//     fp32-equivalent precision, bias via C-init like hidden layers.
//   - A-frags built ONCE per thread via cvt_pkrtz + 12 ds_bpermute, kept in
//     16 VGPRs across the branch loop; identical frag for all quads.
//   - unchanged: tanh4 batched-rcp epilogue, even/odd feature permutation,
//     HROW=72, per-wave LDS h tiles, fdot2 layer 3.

#define NPTS 1048576
#define BLOCK 256
#define HROW 72          // bytes per h row in LDS
#define SCALE 2.8853900817779268f   // 2*log2(e)

// ws layout (bytes):
// 0..16383   : WfH [2][4][2][16][32] f16 (hidden weights, scaled, permuted)
#define OFF_BSC  16384   // Bsc [2][4][2][16] f32 (hidden bias, scaled)
#define OFF_W0F  17408   // W0f [4][2][16][32] f16 (L0 hi/lo packed, scaled)
#define OFF_B0P  25600   // B0p [4][2][16] f32 (L0 bias, scaled, permuted)
#define OFF_W3P  26112   // W3p [4][16] u32 (f16 pairs, unscaled)

using f16   = _Float16;
using f16x8 = __attribute__((ext_vector_type(8))) _Float16;  // MFMA A/B frag
using f32x4 = __attribute__((ext_vector_type(4))) float;     // MFMA C/D frag
using hfx2  = decltype(__builtin_amdgcn_cvt_pkrtz(0.0f, 0.0f)); // __fp16x2

// 4 tanh with ONE v_rcp: inv of product + recovery muls.
// inputs pre-scaled by 2*log2(e): tanh = 1 - 2/(exp2(v)+1)
__device__ __forceinline__ void tanh4_pre(float v0, float v1, float v2, float v3,
                                          float& o0, float& o1, float& o2, float& o3)
{
    float a0 = __builtin_amdgcn_exp2f(v0) + 1.0f;
    float a1 = __builtin_amdgcn_exp2f(v1) + 1.0f;
    float a2 = __builtin_amdgcn_exp2f(v2) + 1.0f;
    float a3 = __builtin_amdgcn_exp2f(v3) + 1.0f;
    float p01  = a0 * a1;
    float p012 = p01 * a2;
    float p    = p012 * a3;
    float r    = __builtin_amdgcn_rcpf(p);
    float inv3 = r * p012;          // 1/a3
    float s    = r * a3;            // 1/p012
    float inv2 = s * p01;           // 1/a2
    float s2   = s * a2;            // 1/p01
    float inv1 = s2 * a0;           // 1/a1
    float inv0 = s2 * a1;           // 1/a0
    o0 = __builtin_fmaf(-2.0f, inv0, 1.0f);
    o1 = __builtin_fmaf(-2.0f, inv1, 1.0f);
    o2 = __builtin_fmaf(-2.0f, inv2, 1.0f);
    o3 = __builtin_fmaf(-2.0f, inv3, 1.0f);
}

// shared MFMA epilogue: tanh4 over (c0[r],c1[r],c0[r+1],c1[r+1]) -> 2 packed b32
__device__ __forceinline__ void mfma_epilogue(const f32x4 (&c)[4][2],
                                              unsigned char* __restrict__ H,
                                              int col, int quad)
{
    #pragma unroll
    for (int mt = 0; mt < 4; ++mt) {
        #pragma unroll
        for (int r = 0; r < 4; r += 2) {
            int p = mt * 16 + quad * 4 + r;
            float o0, o1, o2, o3;
            tanh4_pre(c[mt][0][r], c[mt][1][r],
                      c[mt][0][r + 1], c[mt][1][r + 1], o0, o1, o2, o3);
            union { hfx2 h; unsigned int u; } cv0, cv1;
            cv0.h = __builtin_amdgcn_cvt_pkrtz(o0, o1);
            cv1.h = __builtin_amdgcn_cvt_pkrtz(o2, o3);
            *reinterpret_cast<unsigned int*>(H + p * HROW + 4 * col)       = cv0.u;
            *reinterpret_cast<unsigned int*>(H + (p + 1) * HROW + 4 * col) = cv1.u;
        }
    }
}

__global__ void prep_kernel(const float* __restrict__ W0, const float* __restrict__ b0,
                            const float* __restrict__ W1, const float* __restrict__ b1,
                            const float* __restrict__ W2, const float* __restrict__ b2,
                            const float* __restrict__ W3,
                            unsigned char* __restrict__ ws)
{
    int i = blockIdx.x * 256 + threadIdx.x;
    if (i < 8192) {
        // WfH[l][b][t][n][k] = SCALE * W_l[b][k][2n+t]  (f16)
        int k = i & 31, n = (i >> 5) & 15, t = (i >> 9) & 1, b = (i >> 10) & 3, l = i >> 12;
        int f = 2 * n + t;
        const float* W = l ? W2 : W1;
        reinterpret_cast<f16*>(ws)[i] = (f16)(SCALE * W[(b * 32 + k) * 32 + f]);
    } else if (i < 8448) {
        int j = i - 8192;
        int n = j & 15, t = (j >> 4) & 1, b = (j >> 5) & 3, l = j >> 7;
        const float* bb = l ? b2 : b1;
        reinterpret_cast<float*>(ws + OFF_BSC)[j] = SCALE * bb[b * 32 + 2 * n + t];
    } else if (i < 12544) {
        // W0f[b][t][n][k]: quad q = k>>3, jj = k&7.
        //   q==0, jj<3 : Wh row jj      (pairs with xh -> xh*Wh)
        //   q==0, 3<=jj<6 : Wh row jj-3 (pairs with xl -> xl*Wh)
        //   q==1, jj<3 : Wl row jj      (pairs with xh -> xh*Wl)
        //   else 0
        int j = i - 8448;
        int k = j & 31, n = (j >> 5) & 15, t = (j >> 9) & 1, b = (j >> 10) & 3;
        int f = 2 * n + t;
        int q = k >> 3, jj = k & 7;
        int row = -1; bool lo = false;
        if (q == 0 && jj < 6)      row = (jj < 3) ? jj : jj - 3;
        else if (q == 1 && jj < 3) { row = jj; lo = true; }
        f16 outv = (f16)0.0f;
        if (row >= 0) {
            float w  = SCALE * W0[(b * 3 + row) * 32 + f];
            f16   wh = (f16)w;
            outv = lo ? (f16)(w - (float)wh) : wh;
        }
        reinterpret_cast<f16*>(ws + OFF_W0F)[((b * 2 + t) * 16 + n) * 32 + k] = outv;
    } else if (i < 12672) {
        int j = i - 12544;              // b = j>>5, t = (j>>4)&1, n = j&15
        int n = j & 15, t = (j >> 4) & 1, b = j >> 5;
        reinterpret_cast<float*>(ws + OFF_B0P)[(b * 2 + t) * 16 + n] = SCALE * b0[b * 32 + 2 * n + t];
    } else if (i < 12736) {
        int j = i - 12672;              // j = b*16 + pair
        union { hfx2 h; unsigned int u; } cv;
        cv.h = __builtin_amdgcn_cvt_pkrtz(W3[2 * j], W3[2 * j + 1]);
        reinterpret_cast<unsigned int*>(ws + OFF_W3P)[j] = cv.u;
    }
}

__global__ __launch_bounds__(BLOCK) void pfnn_kernel(
    const float* __restrict__ x, const unsigned char* __restrict__ ws,
    const float* __restrict__ b3,
    float* __restrict__ out)
{
    __shared__ __align__(16) unsigned char Hl[4][64 * HROW]; // per-wave h tile

    const f16*   Wf  = reinterpret_cast<const f16*>(ws);
    const float* Bsc = reinterpret_cast<const float*>(ws + OFF_BSC);
    const f16*   W0f = reinterpret_cast<const f16*>(ws + OFF_W0F);
    const float* B0p = reinterpret_cast<const float*>(ws + OFF_B0P);
    const unsigned int* W3p = reinterpret_cast<const unsigned int*>(ws + OFF_W3P);

    const int t    = threadIdx.x;
    const int lane = t & 63;
    const int wv   = t >> 6;
    const int col  = lane & 15;
    const int quad = lane >> 4;
    unsigned char* __restrict__ H = &Hl[wv][0];

    const int n0 = blockIdx.x * BLOCK + t;
    const float x0 = x[3 * n0 + 0];
    const float x1 = x[3 * n0 + 1];
    const float x2 = x[3 * n0 + 2];

    // ---- build L0 A-frags once: hi/lo f16 split of x, gathered per m-tile ----
    // d0=(xh0,xh1) d1=(xh2,xl0) d2=(xl1,xl2); frag = [d0,d1,d2,0] for ALL quads.
    f16x8 xfrag[4];
    {
        union { hfx2 h; int u; } q0_, q1_, q2_;
        q0_.h = __builtin_amdgcn_cvt_pkrtz(x0, x1);          // RTZ hi parts
        float r0 = x0 - (float)q0_.h[0];
        float r1 = x1 - (float)q0_.h[1];
        q1_.h = __builtin_amdgcn_cvt_pkrtz(x2, r0);
        float r2 = x2 - (float)q1_.h[0];
        q2_.h = __builtin_amdgcn_cvt_pkrtz(r1, r2);
        int d0 = q0_.u, d1 = q1_.u, d2 = q2_.u;
        #pragma unroll
        for (int mt = 0; mt < 4; ++mt) {
            int addr = 4 * (mt * 16 + col);                  // byte addr = lane*4
            union { int i[4]; f16x8 f; } u;
            u.i[0] = __builtin_amdgcn_ds_bpermute(addr, d0);
            u.i[1] = __builtin_amdgcn_ds_bpermute(addr, d1);
            u.i[2] = __builtin_amdgcn_ds_bpermute(addr, d2);
            u.i[3] = 0;
            xfrag[mt] = u.f;
        }
    }

    float res[4];

    #pragma unroll 1
    for (int b = 0; b < 4; ++b) {
        // ---------- layer 0: 3 -> 32 via MFMA (A = xfrag, fp32-equiv) ----------
        {
            const f16* wb = W0f + (b * 2) * 512;
            f16x8 bf0 = *reinterpret_cast<const f16x8*>(wb + col * 32 + quad * 8);
            f16x8 bf1 = *reinterpret_cast<const f16x8*>(wb + 512 + col * 32 + quad * 8);
            float bias0 = B0p[(b * 2 + 0) * 16 + col];  // feature 2*col
            float bias1 = B0p[(b * 2 + 1) * 16 + col];  // feature 2*col+1

            f32x4 c[4][2];
            #pragma unroll
            for (int mt = 0; mt < 4; ++mt) {
                f32x4 c0 = {bias0, bias0, bias0, bias0};
                f32x4 c1 = {bias1, bias1, bias1, bias1};
                c[mt][0] = c0; c[mt][1] = c1;
            }
            #pragma unroll
            for (int mt = 0; mt < 4; ++mt) {
                c[mt][0] = __builtin_amdgcn_mfma_f32_16x16x32_f16(xfrag[mt], bf0, c[mt][0], 0, 0, 0);
                c[mt][1] = __builtin_amdgcn_mfma_f32_16x16x32_f16(xfrag[mt], bf1, c[mt][1], 0, 0, 0);
            }
            mfma_epilogue(c, H, col, quad);
        }

        // ---------- layers 1 & 2: 32 -> 32 via MFMA (unrolled) ----------
        #pragma unroll
        for (int l = 0; l < 2; ++l) {
            const f16* wb = Wf + ((l * 4 + b) * 2) * 512;
            f16x8 bf0 = *reinterpret_cast<const f16x8*>(wb + col * 32 + quad * 8);
            f16x8 bf1 = *reinterpret_cast<const f16x8*>(wb + 512 + col * 32 + quad * 8);
            float bias0 = Bsc[((l * 4 + b) * 2 + 0) * 16 + col]; // feature 2*col
            float bias1 = Bsc[((l * 4 + b) * 2 + 1) * 16 + col]; // feature 2*col+1

            f32x4 c[4][2];
            #pragma unroll
            for (int mt = 0; mt < 4; ++mt) {
                f32x4 c0 = {bias0, bias0, bias0, bias0};
                f32x4 c1 = {bias1, bias1, bias1, bias1};
                c[mt][0] = c0; c[mt][1] = c1;
            }
            #pragma unroll
            for (int mt = 0; mt < 4; ++mt) {
                const unsigned char* arow = H + (mt * 16 + col) * HROW + quad * 16;
                uint2 alo = *reinterpret_cast<const uint2*>(arow);
                uint2 ahi = *reinterpret_cast<const uint2*>(arow + 8);
                union { uint4 u; f16x8 f; } av;
                av.u = make_uint4(alo.x, alo.y, ahi.x, ahi.y);
                c[mt][0] = __builtin_amdgcn_mfma_f32_16x16x32_f16(av.f, bf0, c[mt][0], 0, 0, 0);
                c[mt][1] = __builtin_amdgcn_mfma_f32_16x16x32_f16(av.f, bf1, c[mt][1], 0, 0, 0);
            }
            mfma_epilogue(c, H, col, quad);
        }

        // ---------- layer 3: 32 -> 1 ----------
        {
            float o = b3[b];
            const unsigned char* row = H + lane * HROW;
            const unsigned int* w3p = W3p + b * 16;
            #pragma unroll
            for (int i = 0; i < 8; ++i) {
                uint2 u = *reinterpret_cast<const uint2*>(row + 8 * i);
#if __has_builtin(__builtin_amdgcn_fdot2)
                union { unsigned int uu; hfx2 hh; } h0, h1, w0, w1;
                h0.uu = u.x; h1.uu = u.y;
                w0.uu = w3p[2 * i]; w1.uu = w3p[2 * i + 1];
                o = __builtin_amdgcn_fdot2(h0.hh, w0.hh, o, false);
                o = __builtin_amdgcn_fdot2(h1.hh, w1.hh, o, false);
#else
                union { unsigned int uu; f16 h[2]; } h0, h1, w0, w1;
                h0.uu = u.x; h1.uu = u.y;
                w0.uu = w3p[2 * i]; w1.uu = w3p[2 * i + 1];
                o = __builtin_fmaf((float)h0.h[0], (float)w0.h[0], o);
                o = __builtin_fmaf((float)h0.h[1], (float)w0.h[1], o);
                o = __builtin_fmaf((float)h1.h[0], (float)w1.h[0], o);
                o = __builtin_fmaf((float)h1.h[1], (float)w1.h[1], o);
#endif
            }
            res[b] = o;
        }
    }

    float4 r4 = make_float4(res[0], res[1], res[2], res[3]);
    *reinterpret_cast<float4*>(out + 4 * n0) = r4;
}

extern "C" void kernel_launch(void* const* d_in, const int* in_sizes, int n_in,
                              void* d_out, int out_size, void* d_ws, size_t ws_size,
                              hipStream_t stream) {
    const float* x  = (const float*)d_in[0];
    const float* W0 = (const float*)d_in[1];
    const float* b0 = (const float*)d_in[2];
    const float* W1 = (const float*)d_in[3];
    const float* b1 = (const float*)d_in[4];
    const float* W2 = (const float*)d_in[5];
    const float* b2 = (const float*)d_in[6];
    const float* W3 = (const float*)d_in[7];
    const float* b3 = (const float*)d_in[8];
    float* out = (float*)d_out;
    unsigned char* ws = (unsigned char*)d_ws;

    prep_kernel<<<dim3(50), dim3(256), 0, stream>>>(W0, b0, W1, b1, W2, b2, W3, ws);
    pfnn_kernel<<<dim3(NPTS / BLOCK), dim3(BLOCK), 0, stream>>>(x, ws, b3, out);
}

// Round 2
// 159.734 us; speedup vs baseline: 1.0791x; 1.0791x over previous
//
#include <hip/hip_runtime.h>

// PFNN: 4 branches of 3->32->32->32->1 tanh MLP, N=1M points, fp32 in/out.
// Round 9: occupancy restoration. R8 post-mortem: removing ~500 VALU
// ops/thread gained only 1.2% -> not purely issue-bound; VGPR 64->68 crossed
// the 64-granule (8->7 waves/SIMD HW ceiling) and occupancy fell 37->30%.
// Theory: sizeable latency/stall component; VALUBusy~88% is the gfx94x
// fallback formula overstating issue pressure.
//   - __launch_bounds__(256, 8): force VGPR<=64 -> 8 waves/SIMD ceiling.
//   - per-mt fused MFMA+epilogue: each output tile is ONE MFMA per half
//     (K=32 single shot), so tanh+store right after -> acc liveness 32->8.
//   - shared bias C-init vectors across mt (D!=C legal): 8 movs/layer-branch
//     instead of 32; ~300 fewer v_movs/thread, 24 fewer live regs.
//   - unchanged: MFMA L0 (hi/lo f16 split of x), tanh4 batched-rcp,
//     even/odd feature permutation, HROW=72, fdot2 layer 3.

#define NPTS 1048576
#define BLOCK 256
#define HROW 72          // bytes per h row in LDS
#define SCALE 2.8853900817779268f   // 2*log2(e)

// ws layout (bytes):
// 0..16383   : WfH [2][4][2][16][32] f16 (hidden weights, scaled, permuted)
#define OFF_BSC  16384   // Bsc [2][4][2][16] f32 (hidden bias, scaled)
#define OFF_W0F  17408   // W0f [4][2][16][32] f16 (L0 hi/lo packed, scaled)
#define OFF_B0P  25600   // B0p [4][2][16] f32 (L0 bias, scaled, permuted)
#define OFF_W3P  26112   // W3p [4][16] u32 (f16 pairs, unscaled)

using f16   = _Float16;
using f16x8 = __attribute__((ext_vector_type(8))) _Float16;  // MFMA A/B frag
using f32x4 = __attribute__((ext_vector_type(4))) float;     // MFMA C/D frag
using hfx2  = decltype(__builtin_amdgcn_cvt_pkrtz(0.0f, 0.0f)); // __fp16x2

// 4 tanh with ONE v_rcp: inv of product + recovery muls.
// inputs pre-scaled by 2*log2(e): tanh = 1 - 2/(exp2(v)+1)
__device__ __forceinline__ void tanh4_pre(float v0, float v1, float v2, float v3,
                                          float& o0, float& o1, float& o2, float& o3)
{
    float a0 = __builtin_amdgcn_exp2f(v0) + 1.0f;
    float a1 = __builtin_amdgcn_exp2f(v1) + 1.0f;
    float a2 = __builtin_amdgcn_exp2f(v2) + 1.0f;
    float a3 = __builtin_amdgcn_exp2f(v3) + 1.0f;
    float p01  = a0 * a1;
    float p012 = p01 * a2;
    float p    = p012 * a3;
    float r    = __builtin_amdgcn_rcpf(p);
    float inv3 = r * p012;          // 1/a3
    float s    = r * a3;            // 1/p012
    float inv2 = s * p01;           // 1/a2
    float s2   = s * a2;            // 1/p01
    float inv1 = s2 * a0;           // 1/a1
    float inv0 = s2 * a1;           // 1/a0
    o0 = __builtin_fmaf(-2.0f, inv0, 1.0f);
    o1 = __builtin_fmaf(-2.0f, inv1, 1.0f);
    o2 = __builtin_fmaf(-2.0f, inv2, 1.0f);
    o3 = __builtin_fmaf(-2.0f, inv3, 1.0f);
}

// per-mt epilogue: tanh4 over (c0[r],c1[r],c0[r+1],c1[r+1]) -> 2 packed b32
__device__ __forceinline__ void epi_mt(const f32x4& c0, const f32x4& c1, int mt,
                                       unsigned char* __restrict__ H,
                                       int col, int quad)
{
    #pragma unroll
    for (int r = 0; r < 4; r += 2) {
        int p = mt * 16 + quad * 4 + r;
        float o0, o1, o2, o3;
        tanh4_pre(c0[r], c1[r], c0[r + 1], c1[r + 1], o0, o1, o2, o3);
        union { hfx2 h; unsigned int u; } cv0, cv1;
        cv0.h = __builtin_amdgcn_cvt_pkrtz(o0, o1);
        cv1.h = __builtin_amdgcn_cvt_pkrtz(o2, o3);
        *reinterpret_cast<unsigned int*>(H + p * HROW + 4 * col)       = cv0.u;
        *reinterpret_cast<unsigned int*>(H + (p + 1) * HROW + 4 * col) = cv1.u;
    }
}

__global__ void prep_kernel(const float* __restrict__ W0, const float* __restrict__ b0,
                            const float* __restrict__ W1, const float* __restrict__ b1,
                            const float* __restrict__ W2, const float* __restrict__ b2,
                            const float* __restrict__ W3,
                            unsigned char* __restrict__ ws)
{
    int i = blockIdx.x * 256 + threadIdx.x;
    if (i < 8192) {
        // WfH[l][b][t][n][k] = SCALE * W_l[b][k][2n+t]  (f16)
        int k = i & 31, n = (i >> 5) & 15, t = (i >> 9) & 1, b = (i >> 10) & 3, l = i >> 12;
        int f = 2 * n + t;
        const float* W = l ? W2 : W1;
        reinterpret_cast<f16*>(ws)[i] = (f16)(SCALE * W[(b * 32 + k) * 32 + f]);
    } else if (i < 8448) {
        int j = i - 8192;
        int n = j & 15, t = (j >> 4) & 1, b = (j >> 5) & 3, l = j >> 7;
        const float* bb = l ? b2 : b1;
        reinterpret_cast<float*>(ws + OFF_BSC)[j] = SCALE * bb[b * 32 + 2 * n + t];
    } else if (i < 12544) {
        // W0f[b][t][n][k]: quad q = k>>3, jj = k&7.
        //   q==0, jj<3 : Wh row jj      (pairs with xh -> xh*Wh)
        //   q==0, 3<=jj<6 : Wh row jj-3 (pairs with xl -> xl*Wh)
        //   q==1, jj<3 : Wl row jj      (pairs with xh -> xh*Wl)
        //   else 0
        int j = i - 8448;
        int k = j & 31, n = (j >> 5) & 15, t = (j >> 9) & 1, b = (j >> 10) & 3;
        int f = 2 * n + t;
        int q = k >> 3, jj = k & 7;
        int row = -1; bool lo = false;
        if (q == 0 && jj < 6)      row = (jj < 3) ? jj : jj - 3;
        else if (q == 1 && jj < 3) { row = jj; lo = true; }
        f16 outv = (f16)0.0f;
        if (row >= 0) {
            float w  = SCALE * W0[(b * 3 + row) * 32 + f];
            f16   wh = (f16)w;
            outv = lo ? (f16)(w - (float)wh) : wh;
        }
        reinterpret_cast<f16*>(ws + OFF_W0F)[((b * 2 + t) * 16 + n) * 32 + k] = outv;
    } else if (i < 12672) {
        int j = i - 12544;              // b = j>>5, t = (j>>4)&1, n = j&15
        int n = j & 15, t = (j >> 4) & 1, b = j >> 5;
        reinterpret_cast<float*>(ws + OFF_B0P)[(b * 2 + t) * 16 + n] = SCALE * b0[b * 32 + 2 * n + t];
    } else if (i < 12736) {
        int j = i - 12672;              // j = b*16 + pair
        union { hfx2 h; unsigned int u; } cv;
        cv.h = __builtin_amdgcn_cvt_pkrtz(W3[2 * j], W3[2 * j + 1]);
        reinterpret_cast<unsigned int*>(ws + OFF_W3P)[j] = cv.u;
    }
}

__global__ __launch_bounds__(BLOCK, 8) void pfnn_kernel(
    const float* __restrict__ x, const unsigned char* __restrict__ ws,
    const float* __restrict__ b3,
    float* __restrict__ out)
{
    __shared__ __align__(16) unsigned char Hl[4][64 * HROW]; // per-wave h tile

    const f16*   Wf  = reinterpret_cast<const f16*>(ws);
    const float* Bsc = reinterpret_cast<const float*>(ws + OFF_BSC);
    const f16*   W0f = reinterpret_cast<const f16*>(ws + OFF_W0F);
    const float* B0p = reinterpret_cast<const float*>(ws + OFF_B0P);
    const unsigned int* W3p = reinterpret_cast<const unsigned int*>(ws + OFF_W3P);

    const int t    = threadIdx.x;
    const int lane = t & 63;
    const int wv   = t >> 6;
    const int col  = lane & 15;
    const int quad = lane >> 4;
    unsigned char* __restrict__ H = &Hl[wv][0];

    const int n0 = blockIdx.x * BLOCK + t;
    const float x0 = x[3 * n0 + 0];
    const float x1 = x[3 * n0 + 1];
    const float x2 = x[3 * n0 + 2];

    // ---- build L0 A-frags once: hi/lo f16 split of x, gathered per m-tile ----
    // d0=(xh0,xh1) d1=(xh2,xl0) d2=(xl1,xl2); frag = [d0,d1,d2,0] for ALL quads.
    f16x8 xfrag[4];
    {
        union { hfx2 h; int u; } q0_, q1_, q2_;
        q0_.h = __builtin_amdgcn_cvt_pkrtz(x0, x1);          // RTZ hi parts
        float r0 = x0 - (float)q0_.h[0];
        float r1 = x1 - (float)q0_.h[1];
        q1_.h = __builtin_amdgcn_cvt_pkrtz(x2, r0);
        float r2 = x2 - (float)q1_.h[0];
        q2_.h = __builtin_amdgcn_cvt_pkrtz(r1, r2);
        int d0 = q0_.u, d1 = q1_.u, d2 = q2_.u;
        #pragma unroll
        for (int mt = 0; mt < 4; ++mt) {
            int addr = 4 * (mt * 16 + col);                  // byte addr = lane*4
            union { int i[4]; f16x8 f; } u;
            u.i[0] = __builtin_amdgcn_ds_bpermute(addr, d0);
            u.i[1] = __builtin_amdgcn_ds_bpermute(addr, d1);
            u.i[2] = __builtin_amdgcn_ds_bpermute(addr, d2);
            u.i[3] = 0;
            xfrag[mt] = u.f;
        }
    }

    float res[4];

    #pragma unroll 1
    for (int b = 0; b < 4; ++b) {
        // ---------- layer 0: 3 -> 32 via MFMA (A = xfrag, fp32-equiv) ----------
        {
            const f16* wb = W0f + (b * 2) * 512;
            f16x8 bf0 = *reinterpret_cast<const f16x8*>(wb + col * 32 + quad * 8);
            f16x8 bf1 = *reinterpret_cast<const f16x8*>(wb + 512 + col * 32 + quad * 8);
            float bias0 = B0p[(b * 2 + 0) * 16 + col];  // feature 2*col
            float bias1 = B0p[(b * 2 + 1) * 16 + col];  // feature 2*col+1
            f32x4 ci0 = {bias0, bias0, bias0, bias0};   // shared C operand, all mt
            f32x4 ci1 = {bias1, bias1, bias1, bias1};

            #pragma unroll
            for (int mt = 0; mt < 4; ++mt) {
                f32x4 c0 = __builtin_amdgcn_mfma_f32_16x16x32_f16(xfrag[mt], bf0, ci0, 0, 0, 0);
                f32x4 c1 = __builtin_amdgcn_mfma_f32_16x16x32_f16(xfrag[mt], bf1, ci1, 0, 0, 0);
                epi_mt(c0, c1, mt, H, col, quad);
            }
        }

        // ---------- layers 1 & 2: 32 -> 32 via MFMA (unrolled) ----------
        #pragma unroll
        for (int l = 0; l < 2; ++l) {
            const f16* wb = Wf + ((l * 4 + b) * 2) * 512;
            f16x8 bf0 = *reinterpret_cast<const f16x8*>(wb + col * 32 + quad * 8);
            f16x8 bf1 = *reinterpret_cast<const f16x8*>(wb + 512 + col * 32 + quad * 8);
            float bias0 = Bsc[((l * 4 + b) * 2 + 0) * 16 + col]; // feature 2*col
            float bias1 = Bsc[((l * 4 + b) * 2 + 1) * 16 + col]; // feature 2*col+1
            f32x4 ci0 = {bias0, bias0, bias0, bias0};   // shared C operand, all mt
            f32x4 ci1 = {bias1, bias1, bias1, bias1};

            #pragma unroll
            for (int mt = 0; mt < 4; ++mt) {
                const unsigned char* arow = H + (mt * 16 + col) * HROW + quad * 16;
                uint2 alo = *reinterpret_cast<const uint2*>(arow);
                uint2 ahi = *reinterpret_cast<const uint2*>(arow + 8);
                union { uint4 u; f16x8 f; } av;
                av.u = make_uint4(alo.x, alo.y, ahi.x, ahi.y);
                f32x4 c0 = __builtin_amdgcn_mfma_f32_16x16x32_f16(av.f, bf0, ci0, 0, 0, 0);
                f32x4 c1 = __builtin_amdgcn_mfma_f32_16x16x32_f16(av.f, bf1, ci1, 0, 0, 0);
                epi_mt(c0, c1, mt, H, col, quad);
            }
        }

        // ---------- layer 3: 32 -> 1 ----------
        {
            float o = b3[b];
            const unsigned char* row = H + lane * HROW;
            const unsigned int* w3p = W3p + b * 16;
            #pragma unroll
            for (int i = 0; i < 8; ++i) {
                uint2 u = *reinterpret_cast<const uint2*>(row + 8 * i);
#if __has_builtin(__builtin_amdgcn_fdot2)
                union { unsigned int uu; hfx2 hh; } h0, h1, w0, w1;
                h0.uu = u.x; h1.uu = u.y;
                w0.uu = w3p[2 * i]; w1.uu = w3p[2 * i + 1];
                o = __builtin_amdgcn_fdot2(h0.hh, w0.hh, o, false);
                o = __builtin_amdgcn_fdot2(h1.hh, w1.hh, o, false);
#else
                union { unsigned int uu; f16 h[2]; } h0, h1, w0, w1;
                h0.uu = u.x; h1.uu = u.y;
                w0.uu = w3p[2 * i]; w1.uu = w3p[2 * i + 1];
                o = __builtin_fmaf((float)h0.h[0], (float)w0.h[0], o);
                o = __builtin_fmaf((float)h0.h[1], (float)w0.h[1], o);
                o = __builtin_fmaf((float)h1.h[0], (float)w1.h[0], o);
                o = __builtin_fmaf((float)h1.h[1], (float)w1.h[1], o);
#endif
            }
            res[b] = o;
        }
    }

    float4 r4 = make_float4(res[0], res[1], res[2], res[3]);
    *reinterpret_cast<float4*>(out + 4 * n0) = r4;
}

extern "C" void kernel_launch(void* const* d_in, const int* in_sizes, int n_in,
                              void* d_out, int out_size, void* d_ws, size_t ws_size,
                              hipStream_t stream) {
    const float* x  = (const float*)d_in[0];
    const float* W0 = (const float*)d_in[1];
    const float* b0 = (const float*)d_in[2];
    const float* W1 = (const float*)d_in[3];
    const float* b1 = (const float*)d_in[4];
    const float* W2 = (const float*)d_in[5];
    const float* b2 = (const float*)d_in[6];
    const float* W3 = (const float*)d_in[7];
    const float* b3 = (const float*)d_in[8];
    float* out = (float*)d_out;
    unsigned char* ws = (unsigned char*)d_ws;

    prep_kernel<<<dim3(50), dim3(256), 0, stream>>>(W0, b0, W1, b1, W2, b2, W3, ws);
    pfnn_kernel<<<dim3(NPTS / BLOCK), dim3(BLOCK), 0, stream>>>(x, ws, b3, out);
}

// Round 3
// 152.013 us; speedup vs baseline: 1.1339x; 1.0508x over previous
//
#include <hip/hip_runtime.h>

// PFNN: 4 branches of 3->32->32->32->1 tanh MLP, N=1M points, fp32 in/out.
// Round 10: VALU instruction-count cuts. R9 confirmed occupancy fix (99.8us,
// VGPR 32, occ 66%); now issue-bound on plain VALU count (trans recalibrated
// to ~6-7cy from R6/R7 history, so exp2/rcp are NOT dominant).
//   - centered-inverse folding: store inv' = 1/(exp2(v)+1) - 0.5 in [-.5,.5];
//     h = -2*inv' folded into next layer's weights (W' = -2*SCALE*W, exact
//     f16 exponent shift; biases unchanged, no colsum). The -0.5 folds into
//     the recovery muls (mul->fma). Deletes 4 fma per tanh4 = 384 instr/thr.
//     |inv'|<=0.5 has f16 ulp <= 2^-12 -> same h error as before (4.9e-4).
//   - HROW 72->80 (16B-aligned rows): A-frags via single ds_read_b128
//     (was 2x b64 + assembly), L3 via 4x b128. ~-90 instr/thread.
//     LDS 20480/block = exactly 8 blocks/CU, occupancy ceiling unchanged.
//   - unchanged: MFMA L0 (hi/lo f16 split of x), batched-rcp (wash at
//     trans~7cy), per-mt fused epilogue, launch_bounds(256,8), fdot2 L3.

#define NPTS 1048576
#define BLOCK 256
#define HROW 80          // bytes per h row in LDS (16B aligned)
#define SCALE 2.8853900817779268f   // 2*log2(e)

// ws layout (bytes):
// 0..16383   : WfH [2][4][2][16][32] f16 (hidden weights, -2*SCALE, permuted)
#define OFF_BSC  16384   // Bsc [2][4][2][16] f32 (hidden bias, scaled)
#define OFF_W0F  17408   // W0f [4][2][16][32] f16 (L0 hi/lo packed, scaled)
#define OFF_B0P  25600   // B0p [4][2][16] f32 (L0 bias, scaled, permuted)
#define OFF_W3P  26112   // W3p [4][16] u32 (f16 pairs of -2*w3)

using f16   = _Float16;
using f16x8 = __attribute__((ext_vector_type(8))) _Float16;  // MFMA A/B frag
using f32x4 = __attribute__((ext_vector_type(4))) float;     // MFMA C/D frag
using hfx2  = decltype(__builtin_amdgcn_cvt_pkrtz(0.0f, 0.0f)); // __fp16x2

// 4 centered inverses with ONE v_rcp: o_i = 1/(exp2(v_i)+1) - 0.5.
// (h = tanh = -2*o with pre-scaled v; the -2 is folded into next-layer W.)
__device__ __forceinline__ void inv4c(float v0, float v1, float v2, float v3,
                                      float& o0, float& o1, float& o2, float& o3)
{
    float a0 = __builtin_amdgcn_exp2f(v0) + 1.0f;
    float a1 = __builtin_amdgcn_exp2f(v1) + 1.0f;
    float a2 = __builtin_amdgcn_exp2f(v2) + 1.0f;
    float a3 = __builtin_amdgcn_exp2f(v3) + 1.0f;
    float p01 = a0 * a1;
    float p23 = a2 * a3;
    float p   = p01 * p23;
    float r   = __builtin_amdgcn_rcpf(p);
    float r01 = r * p23;            // 1/(a0*a1)
    float r23 = r * p01;            // 1/(a2*a3)
    o0 = __builtin_fmaf(r01, a1, -0.5f);   // 1/a0 - 0.5
    o1 = __builtin_fmaf(r01, a0, -0.5f);   // 1/a1 - 0.5
    o2 = __builtin_fmaf(r23, a3, -0.5f);   // 1/a2 - 0.5
    o3 = __builtin_fmaf(r23, a2, -0.5f);   // 1/a3 - 0.5
}

// per-mt epilogue: inv4c over (c0[r],c1[r],c0[r+1],c1[r+1]) -> 2 packed b32
__device__ __forceinline__ void epi_mt(const f32x4& c0, const f32x4& c1, int mt,
                                       unsigned char* __restrict__ H,
                                       int col, int quad)
{
    #pragma unroll
    for (int r = 0; r < 4; r += 2) {
        int p = mt * 16 + quad * 4 + r;
        float o0, o1, o2, o3;
        inv4c(c0[r], c1[r], c0[r + 1], c1[r + 1], o0, o1, o2, o3);
        union { hfx2 h; unsigned int u; } cv0, cv1;
        cv0.h = __builtin_amdgcn_cvt_pkrtz(o0, o1);
        cv1.h = __builtin_amdgcn_cvt_pkrtz(o2, o3);
        *reinterpret_cast<unsigned int*>(H + p * HROW + 4 * col)       = cv0.u;
        *reinterpret_cast<unsigned int*>(H + (p + 1) * HROW + 4 * col) = cv1.u;
    }
}

__global__ void prep_kernel(const float* __restrict__ W0, const float* __restrict__ b0,
                            const float* __restrict__ W1, const float* __restrict__ b1,
                            const float* __restrict__ W2, const float* __restrict__ b2,
                            const float* __restrict__ W3,
                            unsigned char* __restrict__ ws)
{
    int i = blockIdx.x * 256 + threadIdx.x;
    if (i < 8192) {
        // WfH[l][b][t][n][k] = -2 * SCALE * W_l[b][k][2n+t]  (f16)
        int k = i & 31, n = (i >> 5) & 15, t = (i >> 9) & 1, b = (i >> 10) & 3, l = i >> 12;
        int f = 2 * n + t;
        const float* W = l ? W2 : W1;
        reinterpret_cast<f16*>(ws)[i] = (f16)(-2.0f * SCALE * W[(b * 32 + k) * 32 + f]);
    } else if (i < 8448) {
        int j = i - 8192;
        int n = j & 15, t = (j >> 4) & 1, b = (j >> 5) & 3, l = j >> 7;
        const float* bb = l ? b2 : b1;
        reinterpret_cast<float*>(ws + OFF_BSC)[j] = SCALE * bb[b * 32 + 2 * n + t];
    } else if (i < 12544) {
        // W0f[b][t][n][k]: quad q = k>>3, jj = k&7.
        //   q==0, jj<3 : Wh row jj      (pairs with xh -> xh*Wh)
        //   q==0, 3<=jj<6 : Wh row jj-3 (pairs with xl -> xl*Wh)
        //   q==1, jj<3 : Wl row jj      (pairs with xh -> xh*Wl)
        //   else 0
        int j = i - 8448;
        int k = j & 31, n = (j >> 5) & 15, t = (j >> 9) & 1, b = (j >> 10) & 3;
        int f = 2 * n + t;
        int q = k >> 3, jj = k & 7;
        int row = -1; bool lo = false;
        if (q == 0 && jj < 6)      row = (jj < 3) ? jj : jj - 3;
        else if (q == 1 && jj < 3) { row = jj; lo = true; }
        f16 outv = (f16)0.0f;
        if (row >= 0) {
            float w  = SCALE * W0[(b * 3 + row) * 32 + f];
            f16   wh = (f16)w;
            outv = lo ? (f16)(w - (float)wh) : wh;
        }
        reinterpret_cast<f16*>(ws + OFF_W0F)[((b * 2 + t) * 16 + n) * 32 + k] = outv;
    } else if (i < 12672) {
        int j = i - 12544;              // b = j>>5, t = (j>>4)&1, n = j&15
        int n = j & 15, t = (j >> 4) & 1, b = j >> 5;
        reinterpret_cast<float*>(ws + OFF_B0P)[(b * 2 + t) * 16 + n] = SCALE * b0[b * 32 + 2 * n + t];
    } else if (i < 12736) {
        int j = i - 12672;              // j = b*16 + pair
        union { hfx2 h; unsigned int u; } cv;
        cv.h = __builtin_amdgcn_cvt_pkrtz(-2.0f * W3[2 * j], -2.0f * W3[2 * j + 1]);
        reinterpret_cast<unsigned int*>(ws + OFF_W3P)[j] = cv.u;
    }
}

__global__ __launch_bounds__(BLOCK, 8) void pfnn_kernel(
    const float* __restrict__ x, const unsigned char* __restrict__ ws,
    const float* __restrict__ b3,
    float* __restrict__ out)
{
    __shared__ __align__(16) unsigned char Hl[4][64 * HROW]; // per-wave h tile

    const f16*   Wf  = reinterpret_cast<const f16*>(ws);
    const float* Bsc = reinterpret_cast<const float*>(ws + OFF_BSC);
    const f16*   W0f = reinterpret_cast<const f16*>(ws + OFF_W0F);
    const float* B0p = reinterpret_cast<const float*>(ws + OFF_B0P);
    const unsigned int* W3p = reinterpret_cast<const unsigned int*>(ws + OFF_W3P);

    const int t    = threadIdx.x;
    const int lane = t & 63;
    const int wv   = t >> 6;
    const int col  = lane & 15;
    const int quad = lane >> 4;
    unsigned char* __restrict__ H = &Hl[wv][0];

    const int n0 = blockIdx.x * BLOCK + t;
    const float x0 = x[3 * n0 + 0];
    const float x1 = x[3 * n0 + 1];
    const float x2 = x[3 * n0 + 2];

    // ---- build L0 A-frags once: hi/lo f16 split of x, gathered per m-tile ----
    // d0=(xh0,xh1) d1=(xh2,xl0) d2=(xl1,xl2); frag = [d0,d1,d2,0] for ALL quads.
    f16x8 xfrag[4];
    {
        union { hfx2 h; int u; } q0_, q1_, q2_;
        q0_.h = __builtin_amdgcn_cvt_pkrtz(x0, x1);          // RTZ hi parts
        float r0 = x0 - (float)q0_.h[0];
        float r1 = x1 - (float)q0_.h[1];
        q1_.h = __builtin_amdgcn_cvt_pkrtz(x2, r0);
        float r2 = x2 - (float)q1_.h[0];
        q2_.h = __builtin_amdgcn_cvt_pkrtz(r1, r2);
        int d0 = q0_.u, d1 = q1_.u, d2 = q2_.u;
        #pragma unroll
        for (int mt = 0; mt < 4; ++mt) {
            int addr = 4 * (mt * 16 + col);                  // byte addr = lane*4
            union { int i[4]; f16x8 f; } u;
            u.i[0] = __builtin_amdgcn_ds_bpermute(addr, d0);
            u.i[1] = __builtin_amdgcn_ds_bpermute(addr, d1);
            u.i[2] = __builtin_amdgcn_ds_bpermute(addr, d2);
            u.i[3] = 0;
            xfrag[mt] = u.f;
        }
    }

    float res[4];

    #pragma unroll 1
    for (int b = 0; b < 4; ++b) {
        // ---------- layer 0: 3 -> 32 via MFMA (A = xfrag, fp32-equiv) ----------
        {
            const f16* wb = W0f + (b * 2) * 512;
            f16x8 bf0 = *reinterpret_cast<const f16x8*>(wb + col * 32 + quad * 8);
            f16x8 bf1 = *reinterpret_cast<const f16x8*>(wb + 512 + col * 32 + quad * 8);
            float bias0 = B0p[(b * 2 + 0) * 16 + col];  // feature 2*col
            float bias1 = B0p[(b * 2 + 1) * 16 + col];  // feature 2*col+1
            f32x4 ci0 = {bias0, bias0, bias0, bias0};   // shared C operand, all mt
            f32x4 ci1 = {bias1, bias1, bias1, bias1};

            #pragma unroll
            for (int mt = 0; mt < 4; ++mt) {
                f32x4 c0 = __builtin_amdgcn_mfma_f32_16x16x32_f16(xfrag[mt], bf0, ci0, 0, 0, 0);
                f32x4 c1 = __builtin_amdgcn_mfma_f32_16x16x32_f16(xfrag[mt], bf1, ci1, 0, 0, 0);
                epi_mt(c0, c1, mt, H, col, quad);
            }
        }

        // ---------- layers 1 & 2: 32 -> 32 via MFMA (unrolled) ----------
        #pragma unroll
        for (int l = 0; l < 2; ++l) {
            const f16* wb = Wf + ((l * 4 + b) * 2) * 512;
            f16x8 bf0 = *reinterpret_cast<const f16x8*>(wb + col * 32 + quad * 8);
            f16x8 bf1 = *reinterpret_cast<const f16x8*>(wb + 512 + col * 32 + quad * 8);
            float bias0 = Bsc[((l * 4 + b) * 2 + 0) * 16 + col]; // feature 2*col
            float bias1 = Bsc[((l * 4 + b) * 2 + 1) * 16 + col]; // feature 2*col+1
            f32x4 ci0 = {bias0, bias0, bias0, bias0};   // shared C operand, all mt
            f32x4 ci1 = {bias1, bias1, bias1, bias1};

            #pragma unroll
            for (int mt = 0; mt < 4; ++mt) {
                const f16x8 av = *reinterpret_cast<const f16x8*>(
                    H + (mt * 16 + col) * HROW + quad * 16);   // 16B aligned
                f32x4 c0 = __builtin_amdgcn_mfma_f32_16x16x32_f16(av, bf0, ci0, 0, 0, 0);
                f32x4 c1 = __builtin_amdgcn_mfma_f32_16x16x32_f16(av, bf1, ci1, 0, 0, 0);
                epi_mt(c0, c1, mt, H, col, quad);
            }
        }

        // ---------- layer 3: 32 -> 1 (weights pre-multiplied by -2) ----------
        {
            float o = b3[b];
            const unsigned char* row = H + lane * HROW;
            const unsigned int* w3p = W3p + b * 16;
            #pragma unroll
            for (int i = 0; i < 4; ++i) {
                uint4 u = *reinterpret_cast<const uint4*>(row + 16 * i);
#if __has_builtin(__builtin_amdgcn_fdot2)
                union { unsigned int uu; hfx2 hh; } h0, h1, h2, h3, w0, w1, w2, w3u;
                h0.uu = u.x; h1.uu = u.y; h2.uu = u.z; h3.uu = u.w;
                w0.uu = w3p[4 * i];     w1.uu = w3p[4 * i + 1];
                w2.uu = w3p[4 * i + 2]; w3u.uu = w3p[4 * i + 3];
                o = __builtin_amdgcn_fdot2(h0.hh, w0.hh, o, false);
                o = __builtin_amdgcn_fdot2(h1.hh, w1.hh, o, false);
                o = __builtin_amdgcn_fdot2(h2.hh, w2.hh, o, false);
                o = __builtin_amdgcn_fdot2(h3.hh, w3u.hh, o, false);
#else
                union { unsigned int uu; f16 h[2]; } hh[4], wwu[4];
                hh[0].uu = u.x; hh[1].uu = u.y; hh[2].uu = u.z; hh[3].uu = u.w;
                #pragma unroll
                for (int q = 0; q < 4; ++q) {
                    wwu[q].uu = w3p[4 * i + q];
                    o = __builtin_fmaf((float)hh[q].h[0], (float)wwu[q].h[0], o);
                    o = __builtin_fmaf((float)hh[q].h[1], (float)wwu[q].h[1], o);
                }
#endif
            }
            res[b] = o;
        }
    }

    float4 r4 = make_float4(res[0], res[1], res[2], res[3]);
    *reinterpret_cast<float4*>(out + 4 * n0) = r4;
}

extern "C" void kernel_launch(void* const* d_in, const int* in_sizes, int n_in,
                              void* d_out, int out_size, void* d_ws, size_t ws_size,
                              hipStream_t stream) {
    const float* x  = (const float*)d_in[0];
    const float* W0 = (const float*)d_in[1];
    const float* b0 = (const float*)d_in[2];
    const float* W1 = (const float*)d_in[3];
    const float* b1 = (const float*)d_in[4];
    const float* W2 = (const float*)d_in[5];
    const float* b2 = (const float*)d_in[6];
    const float* W3 = (const float*)d_in[7];
    const float* b3 = (const float*)d_in[8];
    float* out = (float*)d_out;
    unsigned char* ws = (unsigned char*)d_ws;

    prep_kernel<<<dim3(50), dim3(256), 0, stream>>>(W0, b0, W1, b1, W2, b2, W3, ws);
    pfnn_kernel<<<dim3(NPTS / BLOCK), dim3(BLOCK), 0, stream>>>(x, ws, b3, out);
}